// Round 6
// baseline (123.615 us; speedup 1.0000x reference)
//
#include <hip/hip_runtime.h>
#include <hip/hip_bf16.h>

#define NTOK 1024
#define EMB  1024
#define NH   16
#define HD   64
#define NS   128

typedef unsigned short u16;
typedef unsigned int uint;
typedef __attribute__((ext_vector_type(8))) unsigned short ushort8v;
typedef __attribute__((ext_vector_type(8))) _Float16 half8v;
typedef __attribute__((ext_vector_type(2))) _Float16 h2;
typedef __attribute__((ext_vector_type(4))) float f32x4;

__device__ __forceinline__ u16 f2h_bits(float f) {
  union { _Float16 h; u16 u; } x; x.h = (_Float16)f; return x.u;
}

// ---------------------------------------------------------------------------
// GEMM: C[M,N] = A[M,K] * B[N,K]^T + bias[N], M=N=K=1024, f16 MFMA.
// 64x64 tile, BK=32, 256 threads (4 waves, 2x2 of 32x32), 16 MFMA/k-step.
// ---------------------------------------------------------------------------
template<bool A_F16, bool OUT_F16>
__global__ __launch_bounds__(256) void gemm_t64(
    const void* __restrict__ A0, const void* __restrict__ A1, const void* __restrict__ A2,
    const float* __restrict__ B0, const float* __restrict__ B1, const float* __restrict__ B2,
    const float* __restrict__ b0, const float* __restrict__ b1, const float* __restrict__ b2,
    void* __restrict__ Cp) {
  __shared__ u16 As[64 * 56];
  __shared__ u16 Bs[64 * 56];

  const int t = threadIdx.x;
  const int lane = t & 63;
  const int w = t >> 6;
  const int wr = w >> 1, wc = w & 1;
  const int m0 = blockIdx.y * 64;
  const int n0 = blockIdx.x * 64;
  const int z = blockIdx.z;

  const void*  Asel = (z == 0) ? A0 : ((z == 1) ? A1 : A2);
  const float* Bsel = (z == 0) ? B0 : ((z == 1) ? B1 : B2);
  const float* bsel = (z == 0) ? b0 : ((z == 1) ? b1 : b2);

  const int srow = t >> 2;         // 0..63
  const int scol = (t & 3) * 8;    // 0,8,16,24

  f32x4 acc[2][2];
#pragma unroll
  for (int m = 0; m < 2; m++)
#pragma unroll
    for (int n = 0; n < 2; n++) acc[m][n] = (f32x4){0.f, 0.f, 0.f, 0.f};

  const int fr = lane & 15;
  const int fq = lane >> 4;
  const int kq = fq * 8;

  for (int k0 = 0; k0 < 1024; k0 += 32) {
    if constexpr (A_F16) {
      *(ushort8v*)&As[srow * 56 + scol] =
          *(const ushort8v*)((const u16*)Asel + (size_t)(m0 + srow) * 1024 + k0 + scol);
    } else {
      const float* ap = (const float*)Asel + (size_t)(m0 + srow) * 1024 + k0 + scol;
      const float4 f0 = ((const float4*)ap)[0];
      const float4 f1 = ((const float4*)ap)[1];
      ushort8v p;
      p[0] = f2h_bits(f0.x); p[1] = f2h_bits(f0.y); p[2] = f2h_bits(f0.z); p[3] = f2h_bits(f0.w);
      p[4] = f2h_bits(f1.x); p[5] = f2h_bits(f1.y); p[6] = f2h_bits(f1.z); p[7] = f2h_bits(f1.w);
      *(ushort8v*)&As[srow * 56 + scol] = p;
    }
    {
      const float* bp = Bsel + (size_t)(n0 + srow) * 1024 + k0 + scol;
      const float4 f0 = ((const float4*)bp)[0];
      const float4 f1 = ((const float4*)bp)[1];
      ushort8v p;
      p[0] = f2h_bits(f0.x); p[1] = f2h_bits(f0.y); p[2] = f2h_bits(f0.z); p[3] = f2h_bits(f0.w);
      p[4] = f2h_bits(f1.x); p[5] = f2h_bits(f1.y); p[6] = f2h_bits(f1.z); p[7] = f2h_bits(f1.w);
      *(ushort8v*)&Bs[srow * 56 + scol] = p;
    }
    __syncthreads();

    half8v a[2], b[2];
#pragma unroll
    for (int m = 0; m < 2; m++)
      a[m] = *(const half8v*)&As[(wr * 32 + m * 16 + fr) * 56 + kq];
#pragma unroll
    for (int n = 0; n < 2; n++)
      b[n] = *(const half8v*)&Bs[(wc * 32 + n * 16 + fr) * 56 + kq];
#pragma unroll
    for (int m = 0; m < 2; m++)
#pragma unroll
      for (int n = 0; n < 2; n++)
        acc[m][n] = __builtin_amdgcn_mfma_f32_16x16x32_f16(a[m], b[n], acc[m][n], 0, 0, 0);
    __syncthreads();
  }

  u16*   Cb = (u16*)Cp   + (size_t)z * 1024 * 1024;
  float* Cf = (float*)Cp + (size_t)z * 1024 * 1024;
#pragma unroll
  for (int n = 0; n < 2; n++) {
    const int col = n0 + wc * 32 + n * 16 + fr;
    const float bn = bsel[col];
#pragma unroll
    for (int m = 0; m < 2; m++) {
      const int rbase = m0 + wr * 32 + m * 16 + fq * 4;
#pragma unroll
      for (int r = 0; r < 4; r++) {
        const float val = acc[m][n][r] + bn;
        if constexpr (OUT_F16)
          Cb[(size_t)(rbase + r) * 1024 + col] = f2h_bits(val);
        else
          Cf[(size_t)(rbase + r) * 1024 + col] = val;
      }
    }
  }
}

// ---------------------------------------------------------------------------
// Per-token bitonic sort of the 128 sample indices -> sorted u16 cols.
// ---------------------------------------------------------------------------
__global__ __launch_bounds__(128) void sort_kernel(const int* __restrict__ samples,
                                                   u16* __restrict__ cols) {
  const int row = blockIdx.x;
  const int t = threadIdx.x;
  __shared__ int s[NS];
  s[t] = samples[(size_t)row * NS + t];
  __syncthreads();

  for (unsigned k = 2; k <= NS; k <<= 1) {
    for (unsigned j = k >> 1; j > 0; j >>= 1) {
      const unsigned ixj = t ^ j;
      if (ixj > (unsigned)t) {
        const int a = s[t], b = s[ixj];
        const bool up = ((t & k) == 0);
        if ((up && a > b) || (!up && a < b)) { s[t] = b; s[ixj] = a; }
      }
      __syncthreads();
    }
  }
  cols[(size_t)row * NS + t] = (u16)s[t];
}

// ---------------------------------------------------------------------------
// Attention v5: one wave per (token, head), ZERO barriers.
//  NEW: coalesced K gather. Each wave stages 64 K-row slices (128 B each)
//  into a per-wave LDS buffer: lane = (row-of-8, 16B chunk) -> 8 contiguous
//  rows per load instr (16 mem requests vs 64 for the per-lane scatter).
//  Scores then read LDS (row stride 66 u16 = 33 dwords, odd -> conflict-free)
//  with v_dot2_f32_f16. Two staging halves (samples 0-63, 64-127).
//  Softmax in-wave; PV unchanged (coalesced 4B V loads, packed f16 FMA).
// ---------------------------------------------------------------------------
__global__ __launch_bounds__(256) void attn5(const u16* __restrict__ Qb,
                                             const u16* __restrict__ Kb,
                                             const u16* __restrict__ Vb,
                                             const u16* __restrict__ cols,
                                             u16* __restrict__ O) {
  const int i = blockIdx.y;
  const int wid = threadIdx.x >> 6;
  const int h = blockIdx.x * 4 + wid;
  const int lane = threadIdx.x & 63;

  __shared__ u16 Kg_all[4][64][66];   // per-wave staging (33.8 KB)
  __shared__ uint2 pw[4][NS];         // per-wave (offset, dup'd f16 weight)

  u16 (* __restrict__ Kg)[66] = Kg_all[wid];

  // ---- sample columns + dup flags (cols are sorted) ----
  const int c0 = (int)cols[(size_t)i * NS + lane];
  const int c1 = (int)cols[(size_t)i * NS + 64 + lane];
  const int cp0 = __shfl_up(c0, 1, 64);
  int cp1 = __shfl_up(c1, 1, 64);
  const int c0_63 = __builtin_amdgcn_readlane(c0, 63);
  if (lane == 0) cp1 = c0_63;
  const bool dup0 = (lane > 0) && (c0 == cp0);
  const bool dup1 = (c1 == cp1);

  // ---- q row as 32 half2 ----
  union U8 { ushort8v v; h2 h[4]; };
  U8 qu[8];
  {
    const ushort8v* qp = (const ushort8v*)(Qb + (size_t)i * EMB + h * HD);
#pragma unroll
    for (int j = 0; j < 8; j++) qu[j].v = qp[j];
  }

  const int srow = lane >> 3;     // 0..7 (row within group of 8)
  const int schunk = lane & 7;    // 16B chunk within 128B row slice
  const u16* kslice = Kb + h * HD + schunk * 8;

  // ---- half A: stage K rows for samples 0..63, then score s0 ----
#pragma unroll
  for (int ii = 0; ii < 8; ii++) {
    const int r = srow + ii * 8;
    const int cr = __shfl(c0, r, 64);
    *(ushort8v*)&Kg[r][schunk * 8] = *(const ushort8v*)(kslice + (size_t)cr * EMB);
  }
  asm volatile("s_waitcnt lgkmcnt(0)" ::: "memory");

  float s0a = 0.f, s0b = 0.f;
#pragma unroll
  for (int j = 0; j < 8; j++) {
    U8 kv; kv.v = *(const ushort8v*)&Kg[lane][j * 8];
    s0a = __builtin_amdgcn_fdot2(qu[j].h[0], kv.h[0], s0a, false);
    s0b = __builtin_amdgcn_fdot2(qu[j].h[1], kv.h[1], s0b, false);
    s0a = __builtin_amdgcn_fdot2(qu[j].h[2], kv.h[2], s0a, false);
    s0b = __builtin_amdgcn_fdot2(qu[j].h[3], kv.h[3], s0b, false);
  }
  asm volatile("s_waitcnt lgkmcnt(0)" ::: "memory");

  // ---- half B: stage K rows for samples 64..127, then score s1 ----
#pragma unroll
  for (int ii = 0; ii < 8; ii++) {
    const int r = srow + ii * 8;
    const int cr = __shfl(c1, r, 64);
    *(ushort8v*)&Kg[r][schunk * 8] = *(const ushort8v*)(kslice + (size_t)cr * EMB);
  }
  asm volatile("s_waitcnt lgkmcnt(0)" ::: "memory");

  float s1a = 0.f, s1b = 0.f;
#pragma unroll
  for (int j = 0; j < 8; j++) {
    U8 kv; kv.v = *(const ushort8v*)&Kg[lane][j * 8];
    s1a = __builtin_amdgcn_fdot2(qu[j].h[0], kv.h[0], s1a, false);
    s1b = __builtin_amdgcn_fdot2(qu[j].h[1], kv.h[1], s1b, false);
    s1a = __builtin_amdgcn_fdot2(qu[j].h[2], kv.h[2], s1a, false);
    s1b = __builtin_amdgcn_fdot2(qu[j].h[3], kv.h[3], s1b, false);
  }

  float s0 = dup0 ? -1e30f : (s0a + s0b) * 0.03125f;  // 1/sqrt(1024)
  float s1 = dup1 ? -1e30f : (s1a + s1b) * 0.03125f;

  // ---- in-wave softmax over 128 values ----
  float mx = fmaxf(s0, s1);
#pragma unroll
  for (int off = 32; off > 0; off >>= 1) mx = fmaxf(mx, __shfl_xor(mx, off, 64));
  const float e0 = __expf(s0 - mx);
  const float e1 = __expf(s1 - mx);
  float sm = e0 + e1;
#pragma unroll
  for (int off = 32; off > 0; off >>= 1) sm += __shfl_xor(sm, off, 64);
  const float inv = 1.0f / sm;

  // ---- publish (offset, weight) pairs to LDS (same-wave visibility) ----
  pw[wid][lane]      = make_uint2((uint)c0 * EMB, (uint)f2h_bits(e0 * inv) * 0x10001u);
  pw[wid][64 + lane] = make_uint2((uint)c1 * EMB, (uint)f2h_bits(e1 * inv) * 0x10001u);

  // ---- PV: lane = (sample-half, dim-pair), packed f16 FMA ----
  const int half = lane >> 5;
  const int dp = lane & 31;
  const uint boff = (uint)(h * HD + 2 * dp);
  const uint2* pwp = &pw[wid][half * 64];
  h2 acc = (h2){(_Float16)0.f, (_Float16)0.f};
#pragma unroll 8
  for (int s = 0; s < 64; s++) {
    const uint2 e = pwp[s];
    union { uint u; h2 h; } v, ww;
    v.u = *(const uint*)(Vb + e.x + boff);
    ww.u = e.y;
    acc += v.h * ww.h;
  }
  float o0 = (float)acc[0];
  float o1 = (float)acc[1];
  o0 += __shfl_xor(o0, 32, 64);
  o1 += __shfl_xor(o1, 32, 64);
  if (lane < 32) {
    const uint ob = (uint)f2h_bits(o0) | ((uint)f2h_bits(o1) << 16);
    *(uint*)(O + (size_t)i * EMB + h * HD + 2 * dp) = ob;
  }
}

extern "C" void kernel_launch(void* const* d_in, const int* in_sizes, int n_in,
                              void* d_out, int out_size, void* d_ws, size_t ws_size,
                              hipStream_t stream) {
  const float* query = (const float*)d_in[0];
  const float* key   = (const float*)d_in[1];
  const float* value = (const float*)d_in[2];
  const float* Wq    = (const float*)d_in[3];
  const float* bq    = (const float*)d_in[4];
  const float* Wk    = (const float*)d_in[5];
  const float* bk    = (const float*)d_in[6];
  const float* Wv    = (const float*)d_in[7];
  const float* bv    = (const float*)d_in[8];
  const float* Wo    = (const float*)d_in[9];
  const float* bo    = (const float*)d_in[10];
  const int* samples = (const int*)d_in[11];
  float* out = (float*)d_out;

  // ws layout (f16): Qh,Kh,Vh,O 2MB each + cols 0.25MB = 8.25 MB total
  u16* Qh = (u16*)d_ws;
  u16* Kh = Qh + (size_t)NTOK * EMB;
  u16* Vh = Kh + (size_t)NTOK * EMB;
  u16* O  = Vh + (size_t)NTOK * EMB;
  u16* cols = O + (size_t)NTOK * EMB;

  sort_kernel<<<NTOK, NS, 0, stream>>>(samples, cols);

  gemm_t64<false, true><<<dim3(16, 16, 3), 256, 0, stream>>>(
      query, key, value, Wq, Wk, Wv, bq, bk, bv, Qh);

  attn5<<<dim3(NH / 4, NTOK), 256, 0, stream>>>(Qh, Kh, Vh, cols, O);

  gemm_t64<true, false><<<dim3(16, 16, 1), 256, 0, stream>>>(
      O, O, O, Wo, Wo, Wo, bo, bo, bo, out);
}

// Round 7
// 79.919 us; speedup vs baseline: 1.5468x; 1.5468x over previous
//
#include <hip/hip_runtime.h>
#include <hip/hip_bf16.h>

#define NTOK 1024
#define EMB  1024
#define NH   16
#define HD   64
#define NS   128

typedef unsigned short u16;
typedef unsigned int uint;
typedef __attribute__((ext_vector_type(8))) unsigned short ushort8v;
typedef __attribute__((ext_vector_type(8))) _Float16 half8v;
typedef __attribute__((ext_vector_type(4))) float f32x4;

__device__ __forceinline__ u16 f2h_bits(float f) {
  union { _Float16 h; u16 u; } x; x.h = (_Float16)f; return x.u;
}

// ---------------------------------------------------------------------------
// GEMM: C[M,N] = A[M,K] * B[N,K]^T + bias[N], M=N=K=1024, f16 MFMA.
// 64x64 tile, BK=32, 256 threads (4 waves, 2x2 of 32x32), 16 MFMA/k-step.
// z==2 in the QKV instantiation writes C TRANSPOSED (Vt[d][token]) so the
// attention PV stage can read V fragments from contiguous rows.
// ---------------------------------------------------------------------------
template<bool A_F16, bool OUT_F16>
__global__ __launch_bounds__(256) void gemm_t64(
    const void* __restrict__ A0, const void* __restrict__ A1, const void* __restrict__ A2,
    const float* __restrict__ B0, const float* __restrict__ B1, const float* __restrict__ B2,
    const float* __restrict__ b0, const float* __restrict__ b1, const float* __restrict__ b2,
    void* __restrict__ Cp) {
  __shared__ u16 As[64 * 56];
  __shared__ u16 Bs[64 * 56];

  const int t = threadIdx.x;
  const int lane = t & 63;
  const int w = t >> 6;
  const int wr = w >> 1, wc = w & 1;
  const int m0 = blockIdx.y * 64;
  const int n0 = blockIdx.x * 64;
  const int z = blockIdx.z;

  const void*  Asel = (z == 0) ? A0 : ((z == 1) ? A1 : A2);
  const float* Bsel = (z == 0) ? B0 : ((z == 1) ? B1 : B2);
  const float* bsel = (z == 0) ? b0 : ((z == 1) ? b1 : b2);

  const int srow = t >> 2;         // 0..63
  const int scol = (t & 3) * 8;    // 0,8,16,24

  f32x4 acc[2][2];
#pragma unroll
  for (int m = 0; m < 2; m++)
#pragma unroll
    for (int n = 0; n < 2; n++) acc[m][n] = (f32x4){0.f, 0.f, 0.f, 0.f};

  const int fr = lane & 15;
  const int fq = lane >> 4;
  const int kq = fq * 8;

  for (int k0 = 0; k0 < 1024; k0 += 32) {
    if constexpr (A_F16) {
      *(ushort8v*)&As[srow * 56 + scol] =
          *(const ushort8v*)((const u16*)Asel + (size_t)(m0 + srow) * 1024 + k0 + scol);
    } else {
      const float* ap = (const float*)Asel + (size_t)(m0 + srow) * 1024 + k0 + scol;
      const float4 f0 = ((const float4*)ap)[0];
      const float4 f1 = ((const float4*)ap)[1];
      ushort8v p;
      p[0] = f2h_bits(f0.x); p[1] = f2h_bits(f0.y); p[2] = f2h_bits(f0.z); p[3] = f2h_bits(f0.w);
      p[4] = f2h_bits(f1.x); p[5] = f2h_bits(f1.y); p[6] = f2h_bits(f1.z); p[7] = f2h_bits(f1.w);
      *(ushort8v*)&As[srow * 56 + scol] = p;
    }
    {
      const float* bp = Bsel + (size_t)(n0 + srow) * 1024 + k0 + scol;
      const float4 f0 = ((const float4*)bp)[0];
      const float4 f1 = ((const float4*)bp)[1];
      ushort8v p;
      p[0] = f2h_bits(f0.x); p[1] = f2h_bits(f0.y); p[2] = f2h_bits(f0.z); p[3] = f2h_bits(f0.w);
      p[4] = f2h_bits(f1.x); p[5] = f2h_bits(f1.y); p[6] = f2h_bits(f1.z); p[7] = f2h_bits(f1.w);
      *(ushort8v*)&Bs[srow * 56 + scol] = p;
    }
    __syncthreads();

    half8v a[2], b[2];
#pragma unroll
    for (int m = 0; m < 2; m++)
      a[m] = *(const half8v*)&As[(wr * 32 + m * 16 + fr) * 56 + kq];
#pragma unroll
    for (int n = 0; n < 2; n++)
      b[n] = *(const half8v*)&Bs[(wc * 32 + n * 16 + fr) * 56 + kq];
#pragma unroll
    for (int m = 0; m < 2; m++)
#pragma unroll
      for (int n = 0; n < 2; n++)
        acc[m][n] = __builtin_amdgcn_mfma_f32_16x16x32_f16(a[m], b[n], acc[m][n], 0, 0, 0);
    __syncthreads();
  }

  u16*   Cb = (u16*)Cp   + (size_t)z * 1024 * 1024;
  float* Cf = (float*)Cp + (size_t)z * 1024 * 1024;

  if (OUT_F16 && z == 2) {
    // transposed store: Vt[col][row], 4 consecutive rows pack into one 8B store
#pragma unroll
    for (int n = 0; n < 2; n++) {
      const int col = n0 + wc * 32 + n * 16 + fr;
      const float bn = bsel[col];
#pragma unroll
      for (int m = 0; m < 2; m++) {
        const int rbase = m0 + wr * 32 + m * 16 + fq * 4;
        ushort4 pk;
        pk.x = f2h_bits(acc[m][n][0] + bn);
        pk.y = f2h_bits(acc[m][n][1] + bn);
        pk.z = f2h_bits(acc[m][n][2] + bn);
        pk.w = f2h_bits(acc[m][n][3] + bn);
        *(ushort4*)&Cb[(size_t)col * 1024 + rbase] = pk;
      }
    }
    return;
  }

#pragma unroll
  for (int n = 0; n < 2; n++) {
    const int col = n0 + wc * 32 + n * 16 + fr;
    const float bn = bsel[col];
#pragma unroll
    for (int m = 0; m < 2; m++) {
      const int rbase = m0 + wr * 32 + m * 16 + fq * 4;
#pragma unroll
      for (int r = 0; r < 4; r++) {
        const float val = acc[m][n][r] + bn;
        if constexpr (OUT_F16)
          Cb[(size_t)(rbase + r) * 1024 + col] = f2h_bits(val);
        else
          Cf[(size_t)(rbase + r) * 1024 + col] = val;
      }
    }
  }
}

// ---------------------------------------------------------------------------
// Sampled-set bitmask: mask[i] has bit j set iff j ∈ samples[i,:].
// Duplicate samples collapse automatically (reference masks dups to -1e30,
// i.e. softmax is over the unique set). No sort needed.
// ---------------------------------------------------------------------------
__global__ __launch_bounds__(128) void mask_build(const int* __restrict__ samples,
                                                  uint* __restrict__ maskg) {
  const int i = blockIdx.x;
  const int t = threadIdx.x;
  __shared__ uint m[32];
  if (t < 32) m[t] = 0u;
  __syncthreads();
  const int c = samples[(size_t)i * NS + t];
  atomicOr(&m[c >> 5], 1u << (c & 31));
  __syncthreads();
  if (t < 32) maskg[(size_t)i * 32 + t] = m[t];
}

// ---------------------------------------------------------------------------
// Dense masked attention, f16 MFMA. Block = (head, 32 q-rows), 128 threads
// (2 waves x 16 q-rows). Per k-tile of 128 keys:
//   stage K[128][64] and Vt[64][128] to LDS (coalesced) ->
//   S = Q·K^T (2 MFMA per 16-key subtile) -> mask + exp (no max shift:
//   |scores| ~ 0.1, softmax is shift-invariant) -> P via per-wave LDS
//   (layout transpose) -> PV MFMA accumulate (f32).
// LDS strides 72/136 u16 keep all b128 accesses at <=2-way conflicts (free).
// ---------------------------------------------------------------------------
__global__ __launch_bounds__(128) void attn6(const u16* __restrict__ Qh,
                                             const u16* __restrict__ Kh,
                                             const u16* __restrict__ Vtg,
                                             const uint* __restrict__ maskg,
                                             u16* __restrict__ O) {
  const int h  = blockIdx.x;
  const int qt = blockIdx.y;
  const int t  = threadIdx.x;
  const int wid = t >> 6;
  const int lane = t & 63;
  const int fr = lane & 15, fq = lane >> 4;

  __shared__ u16 Ks[128][72];       // K tile [key][d]       18.4 KB
  __shared__ u16 Vs[64][136];       // Vt tile [d][key]      17.4 KB
  __shared__ u16 Ps[2][16][136];    // per-wave P [q][key]    8.7 KB
  __shared__ uint Ms[32][32];       // mask words             4.0 KB

  // stage mask rows for this q-tile (visibility covered by first loop barrier)
#pragma unroll
  for (int wi = 0; wi < 8; wi++)
    ((uint*)Ms)[wi * 128 + t] = maskg[(size_t)qt * 32 * 32 + wi * 128 + t];

  // Q fragments (A: row=fr -> q-row, k-elems fq*8.. -> dim)
  half8v qa0, qa1;
  {
    const u16* qp = Qh + (size_t)(qt * 32 + wid * 16 + fr) * EMB + h * HD + fq * 8;
    qa0 = *(const half8v*)qp;
    qa1 = *(const half8v*)(qp + 32);
  }

  f32x4 oacc[4];
#pragma unroll
  for (int ds = 0; ds < 4; ds++) oacc[ds] = (f32x4){0.f, 0.f, 0.f, 0.f};
  float lsum[4] = {0.f, 0.f, 0.f, 0.f};

  for (int kt = 0; kt < 8; kt++) {
    __syncthreads();   // previous tile fully consumed (and mask visible, kt=0)
    {
      const u16* kp = Kh + (size_t)(kt * 128 + (t >> 3)) * EMB + h * HD + (t & 7) * 8;
#pragma unroll
      for (int ii = 0; ii < 8; ii++)
        *(ushort8v*)&Ks[(t >> 3) + ii * 16][(t & 7) * 8] =
            *(const ushort8v*)(kp + (size_t)ii * 16 * EMB);
      const u16* vp = Vtg + (size_t)(h * HD + (t >> 4)) * NTOK + kt * 128 + (t & 15) * 8;
#pragma unroll
      for (int ii = 0; ii < 8; ii++)
        *(ushort8v*)&Vs[(t >> 4) + ii * 8][(t & 15) * 8] =
            *(const ushort8v*)(vp + (size_t)ii * 8 * NTOK);
    }
    __syncthreads();

    // ---- S = Q*K^T, mask, exp, store P (per-wave region) ----
#pragma unroll
    for (int jb = 0; jb < 8; jb++) {
      f32x4 s = (f32x4){0.f, 0.f, 0.f, 0.f};
      const half8v b0 = *(const half8v*)&Ks[jb * 16 + fr][fq * 8];
      const half8v b1 = *(const half8v*)&Ks[jb * 16 + fr][32 + fq * 8];
      s = __builtin_amdgcn_mfma_f32_16x16x32_f16(qa0, b0, s, 0, 0, 0);
      s = __builtin_amdgcn_mfma_f32_16x16x32_f16(qa1, b1, s, 0, 0, 0);
      const int mword = (kt * 128 + jb * 16) >> 5;
      const int mbit  = (jb & 1) * 16 + fr;
#pragma unroll
      for (int r = 0; r < 4; r++) {
        const uint mw = Ms[wid * 16 + fq * 4 + r][mword];
        const float p = ((mw >> mbit) & 1u) ? __expf(s[r] * 0.03125f) : 0.f;
        lsum[r] += p;
        Ps[wid][fq * 4 + r][jb * 16 + fr] = f2h_bits(p);
      }
    }
    asm volatile("s_waitcnt lgkmcnt(0)" ::: "memory");

    // ---- PV: O += P * V ----
#pragma unroll
    for (int jc = 0; jc < 4; jc++) {
      const half8v pa = *(const half8v*)&Ps[wid][fr][jc * 32 + fq * 8];
#pragma unroll
      for (int ds = 0; ds < 4; ds++) {
        const half8v vb = *(const half8v*)&Vs[ds * 16 + fr][jc * 32 + fq * 8];
        oacc[ds] = __builtin_amdgcn_mfma_f32_16x16x32_f16(pa, vb, oacc[ds], 0, 0, 0);
      }
    }
  }

  // ---- row sums: reduce over the 16 lanes sharing a q-row group ----
#pragma unroll
  for (int r = 0; r < 4; r++) {
    float v = lsum[r];
#pragma unroll
    for (int off = 1; off < 16; off <<= 1) v += __shfl_xor(v, off, 16);
    lsum[r] = v;
  }

#pragma unroll
  for (int ds = 0; ds < 4; ds++) {
#pragma unroll
    for (int r = 0; r < 4; r++) {
      O[(size_t)(qt * 32 + wid * 16 + fq * 4 + r) * EMB + h * HD + ds * 16 + fr] =
          f2h_bits(oacc[ds][r] / lsum[r]);
    }
  }
}

extern "C" void kernel_launch(void* const* d_in, const int* in_sizes, int n_in,
                              void* d_out, int out_size, void* d_ws, size_t ws_size,
                              hipStream_t stream) {
  const float* query = (const float*)d_in[0];
  const float* key   = (const float*)d_in[1];
  const float* value = (const float*)d_in[2];
  const float* Wq    = (const float*)d_in[3];
  const float* bq    = (const float*)d_in[4];
  const float* Wk    = (const float*)d_in[5];
  const float* bk    = (const float*)d_in[6];
  const float* Wv    = (const float*)d_in[7];
  const float* bv    = (const float*)d_in[8];
  const float* Wo    = (const float*)d_in[9];
  const float* bo    = (const float*)d_in[10];
  const int* samples = (const int*)d_in[11];
  float* out = (float*)d_out;

  // ws layout (f16): Qh,Kh 2MB; Vt 2MB (transposed); O 2MB; mask 128KB = 8.125MB
  u16* Qh = (u16*)d_ws;
  u16* Kh = Qh + (size_t)NTOK * EMB;
  u16* Vt = Kh + (size_t)NTOK * EMB;
  u16* O  = Vt + (size_t)NTOK * EMB;
  uint* maskg = (uint*)(O + (size_t)NTOK * EMB);

  mask_build<<<NTOK, NS, 0, stream>>>(samples, maskg);

  gemm_t64<false, true><<<dim3(16, 16, 3), 256, 0, stream>>>(
      query, key, value, Wq, Wk, Wv, bq, bk, bv, Qh);

  attn6<<<dim3(NH, 32), 128, 0, stream>>>(Qh, Kh, Vt, maskg, O);

  gemm_t64<true, false><<<dim3(16, 16, 1), 256, 0, stream>>>(
      O, O, O, Wo, Wo, Wo, bo, bo, bo, out);
}